// Round 6
// baseline (389.265 us; speedup 1.0000x reference)
//
#include <hip/hip_runtime.h>
#include <math.h>

#define NUM_TOKENS 16384
#define HIDDEN 2048
#define NUM_EXPERTS 64

// out layout (fp32 flat): [0,32768) weights [t][2]; [32768,65536) indices as float; [65536] aux
#define IDX_OFF 32768
#define AUX_OFF 65536

#define TPW 8                    // tokens per wave
#define WPB 4                    // waves per block
#define TPB (TPW * WPB)          // 32 tokens per block
#define NBLK (NUM_TOKENS / TPB)  // 512 blocks
#define PF_DIST 256              // k-distance of L2 prefetch
#define WS_DUMMY (NBLK * 128)    // dummy slots after aux partials

// lane = expert. W[k][lane] is the per-lane VGPR operand (coalesced 256B/instr,
// vmcnt domain -> pipelineable, static 4-deep ring). x[t][k] is wave-uniform ->
// s_load float4 chunks (32B/k only), double-buffered, with explicit vector-domain
// L2 prefetch so the s_loads always hit L2.
__global__ __launch_bounds__(256, 2) void router_kernel(
    const float* __restrict__ x, const float* __restrict__ Wg,
    float* __restrict__ out, float* __restrict__ ws)
{
    __shared__ float sP[WPB][NUM_EXPERTS];
    __shared__ float sC[WPB][NUM_EXPERTS];

    const int tid  = threadIdx.x;
    const int wid  = __builtin_amdgcn_readfirstlane(tid >> 6);
    const int lane = tid & 63;
    const int tok0 = blockIdx.x * TPB + wid * TPW;
    const float* __restrict__ xb = x + (size_t)tok0 * HIDDEN;  // wave-uniform base

    float C[TPW];
    #pragma unroll
    for (int t = 0; t < TPW; ++t) C[t] = 0.f;

    float  w4[4][4];      // 4-chunk-deep W ring (VGPRs), all indices static
    float4 xbuf[2][TPW];  // x double buffer (SGPRs when scalarized)
    float  pfv[8];        // prefetch ring (vector domain)
    float  pfw[8];        // prologue line-warm loads
    float  pf_acc = 0.f;

    // prologue: warm first PF_DIST k of each row's lines (lane*4 spans 1KB = 8 lines)
    #pragma unroll
    for (int r = 0; r < TPW; ++r) pfw[r] = xb[(size_t)r * HIDDEN + (lane << 2)];
    #pragma unroll
    for (int j = 0; j < 8; ++j) pfv[j] = 0.f;
    // x chunk 0, W chunks 0 and 1
    #pragma unroll
    for (int t = 0; t < TPW; ++t)
        xbuf[0][t] = *reinterpret_cast<const float4*>(xb + (size_t)t * HIDDEN);
    #pragma unroll
    for (int j = 0; j < 2; ++j)
        #pragma unroll
        for (int q = 0; q < 4; ++q)
            w4[j][q] = Wg[(size_t)(j * 4 + q) * NUM_EXPERTS + lane];

    for (int kb = 0; kb < HIDDEN; kb += 32) {
        #pragma unroll
        for (int j = 0; j < 8; ++j) {           // chunk = 4 k
            const int k = kb + j * 4;
            // issue next x chunk into the other buffer (s_load, scalar domain)
            {
                const int kn  = k + 4;
                const int knn = (kn == HIDDEN) ? 0 : kn;   // tail-safe
                #pragma unroll
                for (int t = 0; t < TPW; ++t)
                    xbuf[(j + 1) & 1][t] =
                        *reinterpret_cast<const float4*>(xb + (size_t)t * HIDDEN + knn);
            }
            // W ring: load chunk j+2 (vector domain, 256B coalesced per dword)
            {
                const int kw = (k + 8) & (HIDDEN - 1);     // tail wrap, harmless
                #pragma unroll
                for (int q = 0; q < 4; ++q)
                    w4[(j + 2) & 3][q] = Wg[(size_t)(kw + q) * NUM_EXPERTS + lane];
            }
            // L2 prefetch of row j's line at k+PF_DIST (vector domain, 1 line)
            pf_acc += pfv[j];                               // waits load issued 8 chunks ago
            if (kb + PF_DIST < HIDDEN)
                pfv[j] = xb[(size_t)j * HIDDEN + (kb + PF_DIST) + (lane & 31)];
            // FMA: 4 k x 8 tokens; x component uniform (SGPR), w per-lane (VGPR)
            #pragma unroll
            for (int q = 0; q < 4; ++q)
                #pragma unroll
                for (int t = 0; t < TPW; ++t)
                    C[t] = fmaf(reinterpret_cast<const float*>(&xbuf[j & 1][t])[q],
                                w4[j & 3][q], C[t]);
        }
    }

    // keep prefetch loads alive
    #pragma unroll
    for (int j = 0; j < 8; ++j) pf_acc += pfv[j];
    #pragma unroll
    for (int r = 0; r < TPW; ++r) pf_acc += pfw[r];

    // epilogue: per-token wave softmax + top-2 (lane = expert)
    float accP = 0.f, accC = 0.f;
    #pragma unroll
    for (int t = 0; t < TPW; ++t) {
        const float l = C[t];
        float m = l;
        #pragma unroll
        for (int off = 32; off >= 1; off >>= 1) m = fmaxf(m, __shfl_xor(m, off));
        const float p = expf(l - m);
        float Z = p;
        #pragma unroll
        for (int off = 32; off >= 1; off >>= 1) Z += __shfl_xor(Z, off);
        const float prob = p / Z;

        float v1 = prob; int i1 = lane;
        #pragma unroll
        for (int off = 32; off >= 1; off >>= 1) {
            const float ov = __shfl_xor(v1, off);
            const int   oi = __shfl_xor(i1, off);
            if (ov > v1 || (ov == v1 && oi < i1)) { v1 = ov; i1 = oi; }
        }
        float v2 = (lane == i1) ? -1.f : prob; int i2 = lane;
        #pragma unroll
        for (int off = 32; off >= 1; off >>= 1) {
            const float ov = __shfl_xor(v2, off);
            const int   oi = __shfl_xor(i2, off);
            if (ov > v2 || (ov == v2 && oi < i2)) { v2 = ov; i2 = oi; }
        }

        accP += prob;
        accC += (lane == i1) ? 1.f : 0.f;

        if (lane == 0) {
            const float s = v1 + v2 + 1e-9f;
            const size_t o = (size_t)(tok0 + t) * 2;
            float2 wo; wo.x = v1 / s; wo.y = v2 / s;
            *reinterpret_cast<float2*>(&out[o]) = wo;
            float2 io; io.x = (float)i1; io.y = (float)i2;
            *reinterpret_cast<float2*>(&out[IDX_OFF + o]) = io;
        }
    }

    // aux partials: per-block reduce over the 4 waves
    sP[wid][lane] = accP;
    sC[wid][lane] = accC;
    __syncthreads();
    if (tid < 64) {
        const float sp = sP[0][tid] + sP[1][tid] + sP[2][tid] + sP[3][tid];
        const float sc = sC[0][tid] + sC[1][tid] + sC[2][tid] + sC[3][tid];
        ws[(size_t)blockIdx.x * 128 + tid]      = sp;
        ws[(size_t)blockIdx.x * 128 + 64 + tid] = sc;
    }
    if (lane == 0)   // keep prefetch chain live (ws is scratch; value unused)
        ws[WS_DUMMY + (size_t)blockIdx.x * WPB + wid] = pf_acc;
}

__global__ __launch_bounds__(64) void finalize_kernel(
    const float* __restrict__ ws, float* __restrict__ out)
{
    const int e = threadIdx.x;  // 0..63
    float sp = 0.f, sc = 0.f;
    for (int b = 0; b < NBLK; ++b) {
        sp += ws[(size_t)b * 128 + e];
        sc += ws[(size_t)b * 128 + 64 + e];
    }
    float val = (sc * (1.0f / NUM_TOKENS)) * (sp * (1.0f / NUM_TOKENS));
    #pragma unroll
    for (int off = 32; off >= 1; off >>= 1) val += __shfl_xor(val, off);
    if (e == 0) out[AUX_OFF] = (float)NUM_EXPERTS * val;
}

extern "C" void kernel_launch(void* const* d_in, const int* in_sizes, int n_in,
                              void* d_out, int out_size, void* d_ws, size_t ws_size,
                              hipStream_t stream) {
    const float* x  = (const float*)d_in[0];
    const float* Wg = (const float*)d_in[1];
    float* out = (float*)d_out;
    float* ws  = (float*)d_ws;

    router_kernel<<<NBLK, 256, 0, stream>>>(x, Wg, out, ws);
    finalize_kernel<<<1, 64, 0, stream>>>(ws, out);
}

// Round 7
// 112.345 us; speedup vs baseline: 3.4649x; 3.4649x over previous
//
#include <hip/hip_runtime.h>
#include <math.h>

#define NUM_TOKENS 16384
#define HIDDEN 2048
#define NUM_EXPERTS 64

// out layout (fp32 flat): [0,32768) weights [t][2]; [32768,65536) indices as float; [65536] aux
#define IDX_OFF 32768
#define AUX_OFF 65536

#define TPW 8                       // tokens per wave
#define WPB 4                       // waves per block (256 threads)
#define TPB (TPW * WPB)             // 32 tokens per block
#define NBLK (NUM_TOKENS / TPB)     // 512 blocks
#define BK 128                      // k per staged W buffer (32 KB)

__device__ __forceinline__ void gll16(const float* g, float* l) {
    __builtin_amdgcn_global_load_lds(
        (const __attribute__((address_space(1))) unsigned int*)g,
        (__attribute__((address_space(3))) unsigned int*)l, 16, 0, 0);
}

// lane = (phase = lane>>4, eq = lane&15). Wave covers 64 experts x 8 tokens,
// each lane accumulates its 4-of-16 k-phase into C[8][4]; phases merge via
// shfl_xor(16/32) at the end. W: distinct-address ds_read_b128 (full LDS BW),
// staged by global_load_lds double-buffer. x: per-lane global float4 ring.
__global__ __launch_bounds__(256, 2) void router_kernel(
    const float* __restrict__ x, const float* __restrict__ Wg,
    float* __restrict__ out, float* __restrict__ ws)
{
    __shared__ float lds_w[2][BK][NUM_EXPERTS];     // 64 KB

    const int tid = threadIdx.x;
    const int w   = tid >> 6;            // wave 0..3
    const int lane = tid & 63;
    const int ph  = lane >> 4;           // k-phase 0..3
    const int eq  = lane & 15;           // expert quad
    const int tok0 = blockIdx.x * TPB + w * TPW;

    float C[TPW][4];
    #pragma unroll
    for (int t = 0; t < TPW; ++t)
        #pragma unroll
        for (int j = 0; j < 4; ++j) C[t][j] = 0.f;

    const float* xrow = x + (size_t)tok0 * HIDDEN + ph * 4;   // per-lane (phase) base

    #define STAGE(buf, kbn) { \
        const float* gsrc = Wg + (size_t)(kbn) * NUM_EXPERTS; \
        float* ldst = &lds_w[buf][0][0]; \
        _Pragma("unroll") \
        for (int i = 0; i < 8; ++i) \
            gll16(gsrc + i * 1024 + tid * 4, ldst + i * 1024 + tid * 4); \
    }

    // prologue: stage BK 0, load x sub-chunk 0
    STAGE(0, 0);
    float4 xA[TPW], xB[TPW];
    #pragma unroll
    for (int t = 0; t < TPW; ++t)
        xA[t] = *reinterpret_cast<const float4*>(xrow + (size_t)t * HIDDEN);
    __syncthreads();

    for (int kb = 0; kb < HIDDEN; kb += BK) {
        const int bsel = (kb >> 7) & 1;
        if (kb + BK < HIDDEN) STAGE(bsel ^ 1, kb + BK);

        #pragma unroll
        for (int ks8 = 0; ks8 < 8; ++ks8) {          // 16-k sub-chunks
            float4* curp = (ks8 & 1) ? xB : xA;      // static under full unroll
            float4* nxtp = (ks8 & 1) ? xA : xB;

            // prefetch next x sub-chunk (wraps harmlessly at end)
            {
                int kn = kb + ks8 * 16 + 16;
                if (kn >= HIDDEN) kn = 0;
                #pragma unroll
                for (int t = 0; t < TPW; ++t)
                    nxtp[t] = *reinterpret_cast<const float4*>(
                        xrow + (size_t)t * HIDDEN + kn);
            }

            // W fragments: 4 distinct-address b128 reads (full BW, no conflict)
            float4 wv[4];
            #pragma unroll
            for (int jj = 0; jj < 4; ++jj)
                wv[jj] = *reinterpret_cast<const float4*>(
                    &lds_w[bsel][ks8 * 16 + ph * 4 + jj][eq * 4]);

            // 128 FMA
            #pragma unroll
            for (int t = 0; t < TPW; ++t) {
                const float xs[4] = {curp[t].x, curp[t].y, curp[t].z, curp[t].w};
                #pragma unroll
                for (int jj = 0; jj < 4; ++jj) {
                    C[t][0] = fmaf(xs[jj], wv[jj].x, C[t][0]);
                    C[t][1] = fmaf(xs[jj], wv[jj].y, C[t][1]);
                    C[t][2] = fmaf(xs[jj], wv[jj].z, C[t][2]);
                    C[t][3] = fmaf(xs[jj], wv[jj].w, C[t][3]);
                }
            }
        }
        __syncthreads();   // drains gll for next buffer; protects buffer swap
    }

    // ---- phase reduction: full logits for (token t, expert eq*4+j) in every lane ----
    #pragma unroll
    for (int t = 0; t < TPW; ++t)
        #pragma unroll
        for (int j = 0; j < 4; ++j) {
            float v = C[t][j];
            v += __shfl_xor(v, 16);
            v += __shfl_xor(v, 32);
            C[t][j] = v;
        }

    // logits -> LDS (reuse buffer 0; stride 68 floats keeps rows 16B-aligned)
    float* logits = &lds_w[0][0][0];
    float* sP = logits + TPB * 68;       // [WPB][64]
    float* sC = sP + WPB * 64;           // [WPB][64]
    if (ph == 0) {
        #pragma unroll
        for (int t = 0; t < TPW; ++t) {
            float4 v; v.x = C[t][0]; v.y = C[t][1]; v.z = C[t][2]; v.w = C[t][3];
            *reinterpret_cast<float4*>(&logits[(w * TPW + t) * 68 + eq * 4]) = v;
        }
    }
    __syncthreads();

    // ---- wave softmax + top-2, lane = expert ----
    float accP = 0.f, accC = 0.f;
    #pragma unroll
    for (int t = 0; t < TPW; ++t) {
        const float l = logits[(w * TPW + t) * 68 + lane];
        float m = l;
        #pragma unroll
        for (int off = 32; off >= 1; off >>= 1) m = fmaxf(m, __shfl_xor(m, off));
        const float p = expf(l - m);
        float Z = p;
        #pragma unroll
        for (int off = 32; off >= 1; off >>= 1) Z += __shfl_xor(Z, off);
        const float prob = p / Z;

        float v1 = prob; int i1 = lane;
        #pragma unroll
        for (int off = 32; off >= 1; off >>= 1) {
            const float ov = __shfl_xor(v1, off);
            const int   oi = __shfl_xor(i1, off);
            if (ov > v1 || (ov == v1 && oi < i1)) { v1 = ov; i1 = oi; }
        }
        float v2 = (lane == i1) ? -1.f : prob; int i2 = lane;
        #pragma unroll
        for (int off = 32; off >= 1; off >>= 1) {
            const float ov = __shfl_xor(v2, off);
            const int   oi = __shfl_xor(i2, off);
            if (ov > v2 || (ov == v2 && oi < i2)) { v2 = ov; i2 = oi; }
        }

        accP += prob;
        accC += (lane == i1) ? 1.f : 0.f;

        if (lane == 0) {
            const float s = v1 + v2 + 1e-9f;
            const size_t o = (size_t)(tok0 + t) * 2;
            float2 wo; wo.x = v1 / s; wo.y = v2 / s;
            *reinterpret_cast<float2*>(&out[o]) = wo;
            float2 io; io.x = (float)i1; io.y = (float)i2;
            *reinterpret_cast<float2*>(&out[IDX_OFF + o]) = io;
        }
    }

    // ---- aux partials ----
    sP[w * 64 + lane] = accP;
    sC[w * 64 + lane] = accC;
    __syncthreads();
    if (tid < 64) {
        const float sp = sP[tid] + sP[64 + tid] + sP[128 + tid] + sP[192 + tid];
        const float sc = sC[tid] + sC[64 + tid] + sC[128 + tid] + sC[192 + tid];
        ws[(size_t)blockIdx.x * 128 + tid]      = sp;
        ws[(size_t)blockIdx.x * 128 + 64 + tid] = sc;
    }
}

__global__ __launch_bounds__(64) void finalize_kernel(
    const float* __restrict__ ws, float* __restrict__ out)
{
    const int e = threadIdx.x;  // 0..63
    float sp = 0.f, sc = 0.f;
    for (int b = 0; b < NBLK; ++b) {
        sp += ws[(size_t)b * 128 + e];
        sc += ws[(size_t)b * 128 + 64 + e];
    }
    float val = (sc * (1.0f / NUM_TOKENS)) * (sp * (1.0f / NUM_TOKENS));
    #pragma unroll
    for (int off = 32; off >= 1; off >>= 1) val += __shfl_xor(val, off);
    if (e == 0) out[AUX_OFF] = (float)NUM_EXPERTS * val;
}

extern "C" void kernel_launch(void* const* d_in, const int* in_sizes, int n_in,
                              void* d_out, int out_size, void* d_ws, size_t ws_size,
                              hipStream_t stream) {
    const float* x  = (const float*)d_in[0];
    const float* Wg = (const float*)d_in[1];
    float* out = (float*)d_out;
    float* ws  = (float*)d_ws;

    router_kernel<<<NBLK, 256, 0, stream>>>(x, Wg, out, ws);
    finalize_kernel<<<1, 64, 0, stream>>>(ws, out);
}

// Round 8
// 109.000 us; speedup vs baseline: 3.5712x; 1.0307x over previous
//
#include <hip/hip_runtime.h>
#include <math.h>

#define NUM_TOKENS 16384
#define HIDDEN 2048
#define NUM_EXPERTS 64

// out layout (fp32 flat): [0,32768) weights [t][2]; [32768,65536) indices as float; [65536] aux
#define IDX_OFF 32768
#define AUX_OFF 65536

#define TPW 8                       // tokens per wave
#define TPB 32                      // tokens per block (4 waves/group cover them)
#define NBLK (NUM_TOKENS / TPB)     // 512 blocks
#define KG (HIDDEN / 2)             // 1024 k per group
#define BK 32                       // k per staged W buffer (8 KB/group/buf)

typedef float v2f __attribute__((ext_vector_type(2)));

__device__ __forceinline__ void gll16(const float* g, float* l) {
    __builtin_amdgcn_global_load_lds(
        (const __attribute__((address_space(1))) unsigned int*)g,
        (__attribute__((address_space(3))) unsigned int*)l, 16, 0, 0);
}

// 8 waves = 2 k-groups x 4 token-waves. lane = (phase = lane>>4, eq = lane&15).
// Each wave: 8 tokens x 64 experts over its 1024-k half, phase-split 4x.
// W via global_load_lds double-buffer + distinct-address ds_read_b128;
// x per-lane global float4 ring; FMA as v_pk_fma_f32 (float2).
__global__ __launch_bounds__(512, 4) void router_kernel(
    const float* __restrict__ x, const float* __restrict__ Wg,
    float* __restrict__ out, float* __restrict__ ws)
{
    __shared__ float lds_w[2][2][BK][NUM_EXPERTS];   // [group][dbuf][k][e] = 64 KB

    const int tid  = threadIdx.x;
    const int g    = tid >> 8;           // k-group 0/1
    const int wi   = (tid >> 6) & 3;     // wave within group
    const int gtid = tid & 255;
    const int lane = tid & 63;
    const int ph   = lane >> 4;          // k-phase 0..3
    const int eq   = lane & 15;          // expert quad
    const int tok0 = blockIdx.x * TPB + wi * TPW;

    v2f C2[TPW][2];
    #pragma unroll
    for (int t = 0; t < TPW; ++t) { C2[t][0] = (v2f)(0.f); C2[t][1] = (v2f)(0.f); }

    const float* xrow = x + (size_t)tok0 * HIDDEN + g * KG + ph * 4;

    #define STAGE(buf, kbg) { \
        const float* gsrc = Wg + (size_t)(kbg) * NUM_EXPERTS; \
        float* ldst = &lds_w[g][buf][0][0]; \
        _Pragma("unroll") \
        for (int i = 0; i < 2; ++i) \
            gll16(gsrc + (i * 256 + gtid) * 4, ldst + (i * 256 + gtid) * 4); \
    }

    // prologue
    STAGE(0, g * KG);
    float4 xA[TPW], xB[TPW];
    #pragma unroll
    for (int t = 0; t < TPW; ++t)
        xA[t] = *reinterpret_cast<const float4*>(xrow + (size_t)t * HIDDEN);
    __syncthreads();

    for (int kb = 0; kb < KG; kb += BK) {
        const int bsel = (kb >> 5) & 1;
        if (kb + BK < KG) STAGE(bsel ^ 1, g * KG + kb + BK);

        #pragma unroll
        for (int ks = 0; ks < 2; ++ks) {             // 16-k sub-chunks
            float4* curp = ks ? xB : xA;
            float4* nxtp = ks ? xA : xB;

            // prefetch next x sub-chunk (wraps harmlessly at group end)
            {
                int kn = kb + ks * 16 + 16;
                if (kn >= KG) kn = 0;
                #pragma unroll
                for (int t = 0; t < TPW; ++t)
                    nxtp[t] = *reinterpret_cast<const float4*>(
                        xrow + (size_t)t * HIDDEN + kn);
            }

            // W fragments: 4 distinct-address b128 reads
            v2f wv[4][2];
            #pragma unroll
            for (int jj = 0; jj < 4; ++jj) {
                const float4 v = *reinterpret_cast<const float4*>(
                    &lds_w[g][bsel][ks * 16 + ph * 4 + jj][eq * 4]);
                wv[jj][0] = (v2f){v.x, v.y};
                wv[jj][1] = (v2f){v.z, v.w};
            }

            // 64 v_pk_fma_f32 per token-loop (8t x 4jj x 2)
            #pragma unroll
            for (int t = 0; t < TPW; ++t) {
                const float xs[4] = {curp[t].x, curp[t].y, curp[t].z, curp[t].w};
                #pragma unroll
                for (int jj = 0; jj < 4; ++jj) {
                    const v2f xsp = (v2f){xs[jj], xs[jj]};
                    C2[t][0] = __builtin_elementwise_fma(xsp, wv[jj][0], C2[t][0]);
                    C2[t][1] = __builtin_elementwise_fma(xsp, wv[jj][1], C2[t][1]);
                }
            }
        }
        __syncthreads();   // drains gll writes for next buffer; swap-safe
    }

    // ---- phase reduction: sum the 4 k-phases (xor 16, 32) ----
    float Cf[TPW][4];
    #pragma unroll
    for (int t = 0; t < TPW; ++t) {
        Cf[t][0] = C2[t][0].x; Cf[t][1] = C2[t][0].y;
        Cf[t][2] = C2[t][1].x; Cf[t][3] = C2[t][1].y;
        #pragma unroll
        for (int j = 0; j < 4; ++j) {
            float v = Cf[t][j];
            v += __shfl_xor(v, 16);
            v += __shfl_xor(v, 32);
            Cf[t][j] = v;
        }
    }

    // ---- cross-group merge + epilogue (LDS overlay on lds_w) ----
    float* lgB = &lds_w[0][0][0][0];        // [32][68] group-1 partials
    float* lgA = lgB + TPB * 68;            // [32][68] final logits
    float* sP  = lgA + TPB * 68;            // [4][64]
    float* sC  = sP + 4 * 64;               // [4][64]

    if (g == 1 && ph == 0) {
        #pragma unroll
        for (int t = 0; t < TPW; ++t) {
            float4 v; v.x = Cf[t][0]; v.y = Cf[t][1]; v.z = Cf[t][2]; v.w = Cf[t][3];
            *reinterpret_cast<float4*>(&lgB[(wi * TPW + t) * 68 + eq * 4]) = v;
        }
    }
    __syncthreads();

    if (g == 0) {
        #pragma unroll
        for (int t = 0; t < TPW; ++t) {
            const float4 v = *reinterpret_cast<const float4*>(
                &lgB[(wi * TPW + t) * 68 + eq * 4]);
            Cf[t][0] += v.x; Cf[t][1] += v.y; Cf[t][2] += v.z; Cf[t][3] += v.w;
        }
        if (ph == 0) {
            #pragma unroll
            for (int t = 0; t < TPW; ++t) {
                float4 v; v.x = Cf[t][0]; v.y = Cf[t][1]; v.z = Cf[t][2]; v.w = Cf[t][3];
                *reinterpret_cast<float4*>(&lgA[(wi * TPW + t) * 68 + eq * 4]) = v;
            }
        }
    }
    __syncthreads();

    if (g == 0) {
        // wave softmax + top-2, lane = expert
        float accP = 0.f, accC = 0.f;
        #pragma unroll
        for (int t = 0; t < TPW; ++t) {
            const float l = lgA[(wi * TPW + t) * 68 + lane];
            float m = l;
            #pragma unroll
            for (int off = 32; off >= 1; off >>= 1) m = fmaxf(m, __shfl_xor(m, off));
            const float p = expf(l - m);
            float Z = p;
            #pragma unroll
            for (int off = 32; off >= 1; off >>= 1) Z += __shfl_xor(Z, off);
            const float prob = p / Z;

            float v1 = prob; int i1 = lane;
            #pragma unroll
            for (int off = 32; off >= 1; off >>= 1) {
                const float ov = __shfl_xor(v1, off);
                const int   oi = __shfl_xor(i1, off);
                if (ov > v1 || (ov == v1 && oi < i1)) { v1 = ov; i1 = oi; }
            }
            float v2 = (lane == i1) ? -1.f : prob; int i2 = lane;
            #pragma unroll
            for (int off = 32; off >= 1; off >>= 1) {
                const float ov = __shfl_xor(v2, off);
                const int   oi = __shfl_xor(i2, off);
                if (ov > v2 || (ov == v2 && oi < i2)) { v2 = ov; i2 = oi; }
            }

            accP += prob;
            accC += (lane == i1) ? 1.f : 0.f;

            if (lane == 0) {
                const float s = v1 + v2 + 1e-9f;
                const size_t o = (size_t)(tok0 + t) * 2;
                float2 wo; wo.x = v1 / s; wo.y = v2 / s;
                *reinterpret_cast<float2*>(&out[o]) = wo;
                float2 io; io.x = (float)i1; io.y = (float)i2;
                *reinterpret_cast<float2*>(&out[IDX_OFF + o]) = io;
            }
        }
        sP[wi * 64 + lane] = accP;
        sC[wi * 64 + lane] = accC;
    }
    __syncthreads();

    if (tid < 64) {
        const float sp = sP[tid] + sP[64 + tid] + sP[128 + tid] + sP[192 + tid];
        const float sc = sC[tid] + sC[64 + tid] + sC[128 + tid] + sC[192 + tid];
        ws[(size_t)blockIdx.x * 128 + tid]      = sp;
        ws[(size_t)blockIdx.x * 128 + 64 + tid] = sc;
    }
}

__global__ __launch_bounds__(64) void finalize_kernel(
    const float* __restrict__ ws, float* __restrict__ out)
{
    const int e = threadIdx.x;  // 0..63
    float sp = 0.f, sc = 0.f;
    for (int b = 0; b < NBLK; ++b) {
        sp += ws[(size_t)b * 128 + e];
        sc += ws[(size_t)b * 128 + 64 + e];
    }
    float val = (sc * (1.0f / NUM_TOKENS)) * (sp * (1.0f / NUM_TOKENS));
    #pragma unroll
    for (int off = 32; off >= 1; off >>= 1) val += __shfl_xor(val, off);
    if (e == 0) out[AUX_OFF] = (float)NUM_EXPERTS * val;
}

extern "C" void kernel_launch(void* const* d_in, const int* in_sizes, int n_in,
                              void* d_out, int out_size, void* d_ws, size_t ws_size,
                              hipStream_t stream) {
    const float* x  = (const float*)d_in[0];
    const float* Wg = (const float*)d_in[1];
    float* out = (float*)d_out;
    float* ws  = (float*)d_ws;

    router_kernel<<<NBLK, 512, 0, stream>>>(x, Wg, out, ws);
    finalize_kernel<<<1, 64, 0, stream>>>(ws, out);
}